// Round 1
// baseline (5240.063 us; speedup 1.0000x reference)
//
#include <hip/hip_runtime.h>

// Problem constants (match reference setup_inputs)
#define BB   512
#define NN   512
#define NNZ  8192
#define EMB  64
#define HID  100

// ---------------------------------------------------------------------------
// Kernel 1: fused embedding gather + GEMM1  (support1 = emb[hyper] @ W1)
// 64 rows per block, 256 threads. W1 and x-tile staged in LDS (padded),
// each thread computes a 4x4 register tile -> 0.5 LDS reads per FMA.
// ---------------------------------------------------------------------------
__global__ __launch_bounds__(256) void k_embed_gemm1(
    const int* __restrict__ hyper, const float* __restrict__ emb,
    const float* __restrict__ W1, float* __restrict__ out)
{
    __shared__ float xs[64 * 65];      // 64 rows x EMB(64), pad 65
    __shared__ float ws[64 * 101];     // EMB(64) x HID(100), pad 101
    __shared__ int   rid[64];

    const int tid  = threadIdx.x;
    const long base = (long)blockIdx.x * 64;   // row index into [B*N]

    if (tid < 64) rid[tid] = hyper[base + tid];
    for (int i = tid; i < 64 * 100; i += 256) {
        int k = i / 100, h = i % 100;
        ws[k * 101 + h] = W1[i];
    }
    __syncthreads();

    for (int i = tid; i < 64 * 64; i += 256) {
        int r = i >> 6, k = i & 63;
        xs[r * 65 + k] = emb[(long)rid[r] * EMB + k];
    }
    __syncthreads();

    // 400 tasks: 16 row-quads x 25 h-quads
    for (int t = tid; t < 400; t += 256) {
        int rq = t / 25, hq = t % 25;
        int r0 = rq * 4, h0 = hq * 4;
        float acc[4][4] = {};
        #pragma unroll 8
        for (int k = 0; k < EMB; ++k) {
            float a0 = xs[(r0 + 0) * 65 + k];
            float a1 = xs[(r0 + 1) * 65 + k];
            float a2 = xs[(r0 + 2) * 65 + k];
            float a3 = xs[(r0 + 3) * 65 + k];
            float b0 = ws[k * 101 + h0 + 0];
            float b1 = ws[k * 101 + h0 + 1];
            float b2 = ws[k * 101 + h0 + 2];
            float b3 = ws[k * 101 + h0 + 3];
            acc[0][0] += a0 * b0; acc[0][1] += a0 * b1; acc[0][2] += a0 * b2; acc[0][3] += a0 * b3;
            acc[1][0] += a1 * b0; acc[1][1] += a1 * b1; acc[1][2] += a1 * b2; acc[1][3] += a1 * b3;
            acc[2][0] += a2 * b0; acc[2][1] += a2 * b1; acc[2][2] += a2 * b2; acc[2][3] += a2 * b3;
            acc[3][0] += a3 * b0; acc[3][1] += a3 * b1; acc[3][2] += a3 * b2; acc[3][3] += a3 * b3;
        }
        #pragma unroll
        for (int i = 0; i < 4; ++i)
            #pragma unroll
            for (int j = 0; j < 4; ++j)
                out[(size_t)(base + r0 + i) * HID + h0 + j] = acc[i][j];
    }
}

// ---------------------------------------------------------------------------
// Kernel 2/4: batched COO SpMM + bias.
//   out[b,r,:] = sum_k (rows[k]==r) vals[k] * sup[b, cols[k], :] + bias
// One block per (batch, h-half of 50). 512 threads (8 waves), 100 KB LDS acc.
// Each wave loads 64 nnz coalesced, then broadcasts each entry so lanes 0..49
// do one coalesced 200B gather + one ds_add_f32.
// ---------------------------------------------------------------------------
__global__ __launch_bounds__(512) void k_spmm_bias(
    const int* __restrict__ rows, const int* __restrict__ cols,
    const float* __restrict__ vals, const float* __restrict__ sup,
    const float* __restrict__ bias, float* __restrict__ out)
{
    __shared__ float acc[NN * 50];     // 512 x 50 f32 = 100 KB

    const int tid  = threadIdx.x;
    const int b    = blockIdx.x >> 1;
    const int h0   = (blockIdx.x & 1) * 50;

    for (int i = tid; i < NN * 50; i += 512) acc[i] = 0.f;
    __syncthreads();

    const int wave = tid >> 6;
    const int lane = tid & 63;

    const int*   rb = rows + (size_t)b * NNZ;
    const int*   cb = cols + (size_t)b * NNZ;
    const float* vb = vals + (size_t)b * NNZ;
    const float* sb = sup + (size_t)b * NN * HID + h0;

    const int kbeg = wave * (NNZ / 8);
    const int kend = kbeg + (NNZ / 8);
    for (int base = kbeg; base < kend; base += 64) {
        int   r = rb[base + lane];
        int   c = cb[base + lane];
        float v = vb[base + lane];
        #pragma unroll 4
        for (int e = 0; e < 64; ++e) {
            int   re = __shfl(r, e);
            int   ce = __shfl(c, e);
            float ve = __shfl(v, e);
            if (lane < 50) {
                float x = sb[ce * HID + lane];
                atomicAdd(&acc[re * 50 + lane], ve * x);
            }
        }
    }
    __syncthreads();

    for (int i = tid; i < NN * 50; i += 512) {
        int rr = i / 50, hh = i % 50;
        out[((size_t)b * NN + rr) * HID + h0 + hh] = acc[i] + bias[h0 + hh];
    }
}

// ---------------------------------------------------------------------------
// Kernel 3: GEMM2  (support2 = h1 @ W2), K = 100.
// Same structure as kernel 1 but rows come from global (h1).
// ---------------------------------------------------------------------------
__global__ __launch_bounds__(256) void k_gemm2(
    const float* __restrict__ in, const float* __restrict__ W2,
    float* __restrict__ out)
{
    __shared__ float xs[64 * 101];     // 64 rows x 100 k, pad 101 (25.9 KB)
    __shared__ float ws[100 * 101];    // 100 x 100, pad 101 (40.4 KB)

    const int tid  = threadIdx.x;
    const long base = (long)blockIdx.x * 64;

    for (int i = tid; i < 100 * 100; i += 256) {
        int k = i / 100, h = i % 100;
        ws[k * 101 + h] = W2[i];
    }
    for (int i = tid; i < 64 * 100; i += 256) {
        int r = i / 100, k = i % 100;
        xs[r * 101 + k] = in[(size_t)(base + r) * HID + k];
    }
    __syncthreads();

    for (int t = tid; t < 400; t += 256) {
        int rq = t / 25, hq = t % 25;
        int r0 = rq * 4, h0 = hq * 4;
        float acc[4][4] = {};
        #pragma unroll 5
        for (int k = 0; k < HID; ++k) {
            float a0 = xs[(r0 + 0) * 101 + k];
            float a1 = xs[(r0 + 1) * 101 + k];
            float a2 = xs[(r0 + 2) * 101 + k];
            float a3 = xs[(r0 + 3) * 101 + k];
            float b0 = ws[k * 101 + h0 + 0];
            float b1 = ws[k * 101 + h0 + 1];
            float b2 = ws[k * 101 + h0 + 2];
            float b3 = ws[k * 101 + h0 + 3];
            acc[0][0] += a0 * b0; acc[0][1] += a0 * b1; acc[0][2] += a0 * b2; acc[0][3] += a0 * b3;
            acc[1][0] += a1 * b0; acc[1][1] += a1 * b1; acc[1][2] += a1 * b2; acc[1][3] += a1 * b3;
            acc[2][0] += a2 * b0; acc[2][1] += a2 * b1; acc[2][2] += a2 * b2; acc[2][3] += a2 * b3;
            acc[3][0] += a3 * b0; acc[3][1] += a3 * b1; acc[3][2] += a3 * b2; acc[3][3] += a3 * b3;
        }
        #pragma unroll
        for (int i = 0; i < 4; ++i)
            #pragma unroll
            for (int j = 0; j < 4; ++j)
                out[(size_t)(base + r0 + i) * HID + h0 + j] = acc[i][j];
    }
}

// ---------------------------------------------------------------------------
// Launch: support1 -> ws ; h1 -> d_out ; support2 -> ws ; out -> d_out
// Needs ws >= B*N*HID*4 = 104,857,600 bytes.
// ---------------------------------------------------------------------------
extern "C" void kernel_launch(void* const* d_in, const int* in_sizes, int n_in,
                              void* d_out, int out_size, void* d_ws, size_t ws_size,
                              hipStream_t stream)
{
    const int*   hyper = (const int*)  d_in[0];
    const int*   arows = (const int*)  d_in[1];
    const int*   acols = (const int*)  d_in[2];
    const float* avals = (const float*)d_in[3];
    const float* emb   = (const float*)d_in[4];
    const float* W1    = (const float*)d_in[5];
    const float* b1    = (const float*)d_in[6];
    const float* W2    = (const float*)d_in[7];
    const float* b2    = (const float*)d_in[8];

    float* out = (float*)d_out;
    float* scratch = (float*)d_ws;     // [B*N, HID] f32 support buffer

    const int nrows = BB * NN;

    // 1) support1 = emb[hyper] @ W1   -> ws
    k_embed_gemm1<<<nrows / 64, 256, 0, stream>>>(hyper, emb, W1, scratch);
    // 2) h1 = spmm(A, support1) + b1  -> d_out
    k_spmm_bias<<<BB * 2, 512, 0, stream>>>(arows, acols, avals, scratch, b1, out);
    // 3) support2 = h1 @ W2           -> ws
    k_gemm2<<<nrows / 64, 256, 0, stream>>>(out, W2, scratch);
    // 4) out = spmm(A, support2) + b2 -> d_out
    k_spmm_bias<<<BB * 2, 512, 0, stream>>>(arows, acols, avals, scratch, b2, out);
}

// Round 2
// 1094.499 us; speedup vs baseline: 4.7876x; 4.7876x over previous
//
#include <hip/hip_runtime.h>
#include <hip/hip_bf16.h>

// Problem constants (match reference setup_inputs)
#define BB   512
#define NN   512
#define NNZ  8192
#define EMB  64
#define HID  100

// ---------------------------------------------------------------------------
// ws layout (bytes) — total ~88.1 MB (<= the 105 MB proven available):
//   [0)          csr_c   int  [B*NNZ]          16,777,216
//   [16777216)   csr_v   f32  [B*NNZ]          16,777,216
//   [33554432)   row_st  int  [B*513]           1,050,624
//   [34605056)   cursor  int  [B*512]           1,048,576   (also histogram)
//   [35653632)   sup     bf16 [B*N*100]        52,428,800
// ---------------------------------------------------------------------------
#define OFF_CSR_C   0
#define OFF_CSR_V   16777216
#define OFF_ROWST   33554432
#define OFF_CURSOR  34605056
#define OFF_SUP     35653632

// ---------------------------------------------------------------------------
// Kernel 1: fused embedding gather + GEMM1 (support1 = emb[hyper] @ W1) -> bf16
// ---------------------------------------------------------------------------
__global__ __launch_bounds__(256) void k_embed_gemm1(
    const int* __restrict__ hyper, const float* __restrict__ emb,
    const float* __restrict__ W1, __hip_bfloat16* __restrict__ out)
{
    __shared__ float xs[64 * 65];      // 64 rows x EMB(64), pad 65
    __shared__ float ws[64 * 101];     // EMB(64) x HID(100), pad 101
    __shared__ int   rid[64];

    const int tid  = threadIdx.x;
    const long base = (long)blockIdx.x * 64;

    if (tid < 64) rid[tid] = hyper[base + tid];
    for (int i = tid; i < 64 * 100; i += 256) {
        int k = i / 100, h = i % 100;
        ws[k * 101 + h] = W1[i];
    }
    __syncthreads();

    for (int i = tid; i < 64 * 64; i += 256) {
        int r = i >> 6, k = i & 63;
        xs[r * 65 + k] = emb[(long)rid[r] * EMB + k];
    }
    __syncthreads();

    for (int t = tid; t < 400; t += 256) {
        int rq = t / 25, hq = t % 25;
        int r0 = rq * 4, h0 = hq * 4;
        float acc[4][4] = {};
        #pragma unroll 8
        for (int k = 0; k < EMB; ++k) {
            float a0 = xs[(r0 + 0) * 65 + k];
            float a1 = xs[(r0 + 1) * 65 + k];
            float a2 = xs[(r0 + 2) * 65 + k];
            float a3 = xs[(r0 + 3) * 65 + k];
            float b0 = ws[k * 101 + h0 + 0];
            float b1 = ws[k * 101 + h0 + 1];
            float b2 = ws[k * 101 + h0 + 2];
            float b3 = ws[k * 101 + h0 + 3];
            acc[0][0] += a0 * b0; acc[0][1] += a0 * b1; acc[0][2] += a0 * b2; acc[0][3] += a0 * b3;
            acc[1][0] += a1 * b0; acc[1][1] += a1 * b1; acc[1][2] += a1 * b2; acc[1][3] += a1 * b3;
            acc[2][0] += a2 * b0; acc[2][1] += a2 * b1; acc[2][2] += a2 * b2; acc[2][3] += a2 * b3;
            acc[3][0] += a3 * b0; acc[3][1] += a3 * b1; acc[3][2] += a3 * b2; acc[3][3] += a3 * b3;
        }
        #pragma unroll
        for (int i = 0; i < 4; ++i)
            #pragma unroll
            for (int j = 0; j < 4; ++j)
                out[(size_t)(base + r0 + i) * HID + h0 + j] = __float2bfloat16(acc[i][j]);
    }
}

// ---------------------------------------------------------------------------
// CSR build: histogram -> per-batch scan -> scatter. A is shared by both
// SpMM layers, so this runs once per call.
// ---------------------------------------------------------------------------
__global__ __launch_bounds__(256) void k_hist(
    const int* __restrict__ rows, int* __restrict__ counts)
{
    for (int idx = blockIdx.x * 256 + threadIdx.x; idx < BB * NNZ;
         idx += gridDim.x * 256) {
        int b = idx / NNZ;
        int r = rows[idx];
        atomicAdd(&counts[b * NN + r], 1);
    }
}

__global__ __launch_bounds__(512) void k_scan(
    int* __restrict__ cursor /* in: counts, out: exclusive scan */,
    int* __restrict__ row_start)
{
    __shared__ int s[NN];
    const int b = blockIdx.x, t = threadIdx.x;
    const int own = cursor[b * NN + t];
    s[t] = own;
    __syncthreads();
    for (int off = 1; off < NN; off <<= 1) {
        int v = (t >= off) ? s[t - off] : 0;
        __syncthreads();
        s[t] += v;
        __syncthreads();
    }
    // s = inclusive scan
    row_start[b * 513 + t + 1] = s[t];
    if (t == 0) row_start[b * 513] = 0;
    cursor[b * NN + t] = s[t] - own;   // exclusive scan -> scatter cursor
}

__global__ __launch_bounds__(256) void k_scatter(
    const int* __restrict__ rows, const int* __restrict__ cols,
    const float* __restrict__ vals, int* __restrict__ cursor,
    int* __restrict__ csr_c, float* __restrict__ csr_v)
{
    for (int idx = blockIdx.x * 256 + threadIdx.x; idx < BB * NNZ;
         idx += gridDim.x * 256) {
        int b = idx / NNZ;
        int r = rows[idx];
        int pos = atomicAdd(&cursor[b * NN + r], 1);
        csr_c[(size_t)b * NNZ + pos] = cols[idx];
        csr_v[(size_t)b * NNZ + pos] = vals[idx];
    }
}

// ---------------------------------------------------------------------------
// CSR SpMM + bias: one WAVE per output row. ~16 nnz/row; wave-uniform (c,v)
// hoisted to SGPRs, coalesced 200B bf16 gather of sup[c,:], register
// accumulation (no LDS, no atomics), coalesced float2 store.
// 512 threads = 8 waves/block, no LDS -> 4 blocks/CU (32 waves/CU).
// ---------------------------------------------------------------------------
__global__ __launch_bounds__(512) void k_spmm_csr(
    const int* __restrict__ row_start, const int* __restrict__ csr_c,
    const float* __restrict__ csr_v, const __hip_bfloat16* __restrict__ sup,
    const float* __restrict__ bias, float* __restrict__ out)
{
    const int wid  = blockIdx.x * 8 + (threadIdx.x >> 6);  // global row id
    const int lane = threadIdx.x & 63;
    const int b = wid >> 9;
    const int r = wid & (NN - 1);

    const int s = row_start[b * 513 + r];
    const int e = row_start[b * 513 + r + 1];

    const unsigned* supu = (const unsigned*)sup + (size_t)b * NN * 50;  // 50 u32/row
    const int*   cc = csr_c + (size_t)b * NNZ;
    const float* vv = csr_v + (size_t)b * NNZ;

    float acc0 = 0.f, acc1 = 0.f;

    int j = s;
    for (; j + 1 < e; j += 2) {
        int   c0 = __builtin_amdgcn_readfirstlane(cc[j]);
        int   c1 = __builtin_amdgcn_readfirstlane(cc[j + 1]);
        float v0 = __uint_as_float(__builtin_amdgcn_readfirstlane(__float_as_uint(vv[j])));
        float v1 = __uint_as_float(__builtin_amdgcn_readfirstlane(__float_as_uint(vv[j + 1])));
        if (lane < 50) {
            unsigned x0 = supu[(size_t)c0 * 50 + lane];
            unsigned x1 = supu[(size_t)c1 * 50 + lane];
            acc0 += v0 * __uint_as_float(x0 << 16);
            acc1 += v0 * __uint_as_float(x0 & 0xffff0000u);
            acc0 += v1 * __uint_as_float(x1 << 16);
            acc1 += v1 * __uint_as_float(x1 & 0xffff0000u);
        }
    }
    if (j < e) {
        int   c0 = __builtin_amdgcn_readfirstlane(cc[j]);
        float v0 = __uint_as_float(__builtin_amdgcn_readfirstlane(__float_as_uint(vv[j])));
        if (lane < 50) {
            unsigned x0 = supu[(size_t)c0 * 50 + lane];
            acc0 += v0 * __uint_as_float(x0 << 16);
            acc1 += v0 * __uint_as_float(x0 & 0xffff0000u);
        }
    }

    if (lane < 50) {
        float2 bi = ((const float2*)bias)[lane];
        float2 o;
        o.x = acc0 + bi.x;
        o.y = acc1 + bi.y;
        ((float2*)(out + (size_t)wid * HID))[lane] = o;
    }
}

// ---------------------------------------------------------------------------
// Kernel 3: GEMM2 (support2 = h1 @ W2) -> bf16. h1 read fp32 from d_out.
// ---------------------------------------------------------------------------
__global__ __launch_bounds__(256) void k_gemm2(
    const float* __restrict__ in, const float* __restrict__ W2,
    __hip_bfloat16* __restrict__ out)
{
    __shared__ float xs[64 * 101];
    __shared__ float ws[100 * 101];

    const int tid  = threadIdx.x;
    const long base = (long)blockIdx.x * 64;

    for (int i = tid; i < 100 * 100; i += 256) {
        int k = i / 100, h = i % 100;
        ws[k * 101 + h] = W2[i];
    }
    for (int i = tid; i < 64 * 100; i += 256) {
        int r = i / 100, k = i % 100;
        xs[r * 101 + k] = in[(size_t)(base + r) * HID + k];
    }
    __syncthreads();

    for (int t = tid; t < 400; t += 256) {
        int rq = t / 25, hq = t % 25;
        int r0 = rq * 4, h0 = hq * 4;
        float acc[4][4] = {};
        #pragma unroll 5
        for (int k = 0; k < HID; ++k) {
            float a0 = xs[(r0 + 0) * 101 + k];
            float a1 = xs[(r0 + 1) * 101 + k];
            float a2 = xs[(r0 + 2) * 101 + k];
            float a3 = xs[(r0 + 3) * 101 + k];
            float b0 = ws[k * 101 + h0 + 0];
            float b1 = ws[k * 101 + h0 + 1];
            float b2 = ws[k * 101 + h0 + 2];
            float b3 = ws[k * 101 + h0 + 3];
            acc[0][0] += a0 * b0; acc[0][1] += a0 * b1; acc[0][2] += a0 * b2; acc[0][3] += a0 * b3;
            acc[1][0] += a1 * b0; acc[1][1] += a1 * b1; acc[1][2] += a1 * b2; acc[1][3] += a1 * b3;
            acc[2][0] += a2 * b0; acc[2][1] += a2 * b1; acc[2][2] += a2 * b2; acc[2][3] += a2 * b3;
            acc[3][0] += a3 * b0; acc[3][1] += a3 * b1; acc[3][2] += a3 * b2; acc[3][3] += a3 * b3;
        }
        #pragma unroll
        for (int i = 0; i < 4; ++i)
            #pragma unroll
            for (int j = 0; j < 4; ++j)
                out[(size_t)(base + r0 + i) * HID + h0 + j] = __float2bfloat16(acc[i][j]);
    }
}

// ---------------------------------------------------------------------------
extern "C" void kernel_launch(void* const* d_in, const int* in_sizes, int n_in,
                              void* d_out, int out_size, void* d_ws, size_t ws_size,
                              hipStream_t stream)
{
    const int*   hyper = (const int*)  d_in[0];
    const int*   arows = (const int*)  d_in[1];
    const int*   acols = (const int*)  d_in[2];
    const float* avals = (const float*)d_in[3];
    const float* emb   = (const float*)d_in[4];
    const float* W1    = (const float*)d_in[5];
    const float* b1    = (const float*)d_in[6];
    const float* W2    = (const float*)d_in[7];
    const float* b2    = (const float*)d_in[8];

    float* out = (float*)d_out;
    char*  ws  = (char*)d_ws;

    int*             csr_c   = (int*)  (ws + OFF_CSR_C);
    float*           csr_v   = (float*)(ws + OFF_CSR_V);
    int*             row_st  = (int*)  (ws + OFF_ROWST);
    int*             cursor  = (int*)  (ws + OFF_CURSOR);
    __hip_bfloat16*  sup     = (__hip_bfloat16*)(ws + OFF_SUP);

    const int nrows = BB * NN;

    // --- CSR build (A shared by both layers) ---
    hipMemsetAsync(cursor, 0, (size_t)BB * NN * sizeof(int), stream);
    k_hist   <<<4096, 256, 0, stream>>>(arows, cursor);
    k_scan   <<<BB,   512, 0, stream>>>(cursor, row_st);
    k_scatter<<<4096, 256, 0, stream>>>(arows, acols, avals, cursor, csr_c, csr_v);

    // 1) support1 = emb[hyper] @ W1              -> sup (bf16, ws)
    k_embed_gemm1<<<nrows / 64, 256, 0, stream>>>(hyper, emb, W1, sup);
    // 2) h1 = A @ support1 + b1                  -> d_out (fp32)
    k_spmm_csr<<<nrows / 8, 512, 0, stream>>>(row_st, csr_c, csr_v, sup, b1, out);
    // 3) support2 = h1 @ W2                      -> sup (bf16, ws)
    k_gemm2<<<nrows / 64, 256, 0, stream>>>(out, W2, sup);
    // 4) out = A @ support2 + b2                 -> d_out (fp32)
    k_spmm_csr<<<nrows / 8, 512, 0, stream>>>(row_st, csr_c, csr_v, sup, b2, out);
}

// Round 3
// 967.071 us; speedup vs baseline: 5.4185x; 1.1318x over previous
//
#include <hip/hip_runtime.h>
#include <hip/hip_bf16.h>

// Problem constants (match reference setup_inputs)
#define BB   512
#define NN   512
#define NNZ  8192
#define EMB  64
#define HID  100

// ---------------------------------------------------------------------------
// ws layout (bytes):
//   [0)          csr_c   int  [B*NNZ]          16,777,216
//   [16777216)   csr_v   f32  [B*NNZ]          16,777,216
//   [33554432)   row_st  int  [B*513]           1,050,624
//   [34605056)   cursor  int  [B*512]           1,048,576   (also histogram)
//   [35653632)   sup     bf16 [B*N*100]        52,428,800   (u32-pair packed)
// ---------------------------------------------------------------------------
#define OFF_CSR_C   0
#define OFF_CSR_V   16777216
#define OFF_ROWST   33554432
#define OFF_CURSOR  34605056
#define OFF_SUP     35653632

// ---------------------------------------------------------------------------
// Kernel 1: fused embedding gather + GEMM1 (support1 = emb[hyper] @ W1) -> bf16
// ---------------------------------------------------------------------------
__global__ __launch_bounds__(256) void k_embed_gemm1(
    const int* __restrict__ hyper, const float* __restrict__ emb,
    const float* __restrict__ W1, __hip_bfloat16* __restrict__ out)
{
    __shared__ float xs[64 * 65];      // 64 rows x EMB(64), pad 65
    __shared__ float ws[64 * 101];     // EMB(64) x HID(100), pad 101
    __shared__ int   rid[64];

    const int tid  = threadIdx.x;
    const long base = (long)blockIdx.x * 64;

    if (tid < 64) rid[tid] = hyper[base + tid];
    for (int i = tid; i < 64 * 100; i += 256) {
        int k = i / 100, h = i % 100;
        ws[k * 101 + h] = W1[i];
    }
    __syncthreads();

    for (int i = tid; i < 64 * 64; i += 256) {
        int r = i >> 6, k = i & 63;
        xs[r * 65 + k] = emb[(long)rid[r] * EMB + k];
    }
    __syncthreads();

    for (int t = tid; t < 400; t += 256) {
        int rq = t / 25, hq = t % 25;
        int r0 = rq * 4, h0 = hq * 4;
        float acc[4][4] = {};
        #pragma unroll 8
        for (int k = 0; k < EMB; ++k) {
            float a0 = xs[(r0 + 0) * 65 + k];
            float a1 = xs[(r0 + 1) * 65 + k];
            float a2 = xs[(r0 + 2) * 65 + k];
            float a3 = xs[(r0 + 3) * 65 + k];
            float b0 = ws[k * 101 + h0 + 0];
            float b1 = ws[k * 101 + h0 + 1];
            float b2 = ws[k * 101 + h0 + 2];
            float b3 = ws[k * 101 + h0 + 3];
            acc[0][0] += a0 * b0; acc[0][1] += a0 * b1; acc[0][2] += a0 * b2; acc[0][3] += a0 * b3;
            acc[1][0] += a1 * b0; acc[1][1] += a1 * b1; acc[1][2] += a1 * b2; acc[1][3] += a1 * b3;
            acc[2][0] += a2 * b0; acc[2][1] += a2 * b1; acc[2][2] += a2 * b2; acc[2][3] += a2 * b3;
            acc[3][0] += a3 * b0; acc[3][1] += a3 * b1; acc[3][2] += a3 * b2; acc[3][3] += a3 * b3;
        }
        #pragma unroll
        for (int i = 0; i < 4; ++i)
            #pragma unroll
            for (int j = 0; j < 4; ++j)
                out[(size_t)(base + r0 + i) * HID + h0 + j] = __float2bfloat16(acc[i][j]);
    }
}

// ---------------------------------------------------------------------------
// CSR build: histogram -> per-batch scan -> scatter (A shared by both layers)
// ---------------------------------------------------------------------------
__global__ __launch_bounds__(256) void k_hist(
    const int* __restrict__ rows, int* __restrict__ counts)
{
    for (int idx = blockIdx.x * 256 + threadIdx.x; idx < BB * NNZ;
         idx += gridDim.x * 256) {
        int b = idx / NNZ;
        int r = rows[idx];
        atomicAdd(&counts[b * NN + r], 1);
    }
}

__global__ __launch_bounds__(512) void k_scan(
    int* __restrict__ cursor /* in: counts, out: exclusive scan */,
    int* __restrict__ row_start)
{
    __shared__ int s[NN];
    const int b = blockIdx.x, t = threadIdx.x;
    const int own = cursor[b * NN + t];
    s[t] = own;
    __syncthreads();
    for (int off = 1; off < NN; off <<= 1) {
        int v = (t >= off) ? s[t - off] : 0;
        __syncthreads();
        s[t] += v;
        __syncthreads();
    }
    row_start[b * 513 + t + 1] = s[t];
    if (t == 0) row_start[b * 513] = 0;
    cursor[b * NN + t] = s[t] - own;
}

__global__ __launch_bounds__(256) void k_scatter(
    const int* __restrict__ rows, const int* __restrict__ cols,
    const float* __restrict__ vals, int* __restrict__ cursor,
    int* __restrict__ csr_c, float* __restrict__ csr_v)
{
    for (int idx = blockIdx.x * 256 + threadIdx.x; idx < BB * NNZ;
         idx += gridDim.x * 256) {
        int b = idx / NNZ;
        int r = rows[idx];
        int pos = atomicAdd(&cursor[b * NN + r], 1);
        csr_c[(size_t)b * NNZ + pos] = cols[idx];
        csr_v[(size_t)b * NNZ + pos] = vals[idx];
    }
}

// ---------------------------------------------------------------------------
// CSR SpMM + bias, LDS-staged support.
// One block per BATCH (512 blocks, 512 threads, 1 block/CU).
// Stage sup[b] (512 x 50 u32 of packed bf16 = 102.4 KB) + row_start in LDS.
// One wave per row: (c,v) loaded lane-parallel coalesced, broadcast via
// readlane (register-only), gather = conflict-free ds_read_b32, register
// accumulation, next row's (c,v) prefetched during current row's compute.
// ---------------------------------------------------------------------------
__global__ __launch_bounds__(512) void k_spmm_lds(
    const int* __restrict__ row_start, const int* __restrict__ csr_c,
    const float* __restrict__ csr_v, const unsigned* __restrict__ sup,
    const float* __restrict__ bias, float* __restrict__ out)
{
    __shared__ unsigned xls[NN * 50];   // 102,400 B
    __shared__ int      rst[NN + 1];    // +2,052 B (also absorbs dead-lane reads)

    const int tid = threadIdx.x;
    const int b   = blockIdx.x;

    // stage support slice (coalesced uint4)
    {
        const uint4* src = (const uint4*)(sup + (size_t)b * NN * 50);
        uint4* dst = (uint4*)xls;
        #pragma unroll
        for (int i = 0; i < 13; ++i) {
            int idx = tid + i * 512;
            if (idx < NN * 50 / 4) dst[idx] = src[idx];
        }
    }
    for (int i = tid; i < NN + 1; i += 512) rst[i] = row_start[b * (NN + 1) + i];
    __syncthreads();

    const int wave = tid >> 6;
    const int lane = tid & 63;

    const int*   cc = csr_c + (size_t)b * NNZ;
    const float* vv = csr_v + (size_t)b * NNZ;

    float2 bi = make_float2(0.f, 0.f);
    if (lane < 50) bi = ((const float2*)bias)[lane];

    const int r0 = wave * 64;

    // prefetch first row's entries
    int s = rst[r0], e = rst[r0 + 1];
    int c = 0; float v = 0.f;
    if (lane < e - s) { c = cc[s + lane]; v = vv[s + lane]; }

    for (int r = r0; r < r0 + 64; ++r) {
        // prefetch next row (overlaps with this row's LDS compute)
        int sn = 0, en = 0, cn = 0; float vn = 0.f;
        if (r + 1 < r0 + 64) {
            sn = rst[r + 1]; en = rst[r + 2];
            if (lane < en - sn) { cn = cc[sn + lane]; vn = vv[sn + lane]; }
        }

        const int cnt = e - s;
        const int lim = cnt < 64 ? cnt : 64;
        float acc0 = 0.f, acc1 = 0.f;
        for (int j = 0; j < lim; ++j) {
            int   cj = __shfl(c, j);
            float vj = __shfl(v, j);
            // lanes 50..63 read harmless slack (lands in rst), values unused
            unsigned x = xls[cj * 50 + lane];
            acc0 += vj * __uint_as_float(x << 16);
            acc1 += vj * __uint_as_float(x & 0xffff0000u);
        }
        if (cnt > 64) {  // cold path, statistically never (Poisson(16))
            for (int jj = s + 64; jj < e; ++jj) {
                int   cj = cc[jj];
                float vj = vv[jj];
                unsigned x = xls[cj * 50 + lane];
                acc0 += vj * __uint_as_float(x << 16);
                acc1 += vj * __uint_as_float(x & 0xffff0000u);
            }
        }

        if (lane < 50) {
            float2 o;
            o.x = acc0 + bi.x;
            o.y = acc1 + bi.y;
            ((float2*)(out + ((size_t)b * NN + r) * HID))[lane] = o;
        }

        s = sn; e = en; c = cn; v = vn;
    }
}

// ---------------------------------------------------------------------------
// Kernel 3: GEMM2 (support2 = h1 @ W2) -> bf16. h1 read fp32 from d_out.
// ---------------------------------------------------------------------------
__global__ __launch_bounds__(256) void k_gemm2(
    const float* __restrict__ in, const float* __restrict__ W2,
    __hip_bfloat16* __restrict__ out)
{
    __shared__ float xs[64 * 101];
    __shared__ float ws[100 * 101];

    const int tid  = threadIdx.x;
    const long base = (long)blockIdx.x * 64;

    for (int i = tid; i < 100 * 100; i += 256) {
        int k = i / 100, h = i % 100;
        ws[k * 101 + h] = W2[i];
    }
    for (int i = tid; i < 64 * 100; i += 256) {
        int r = i / 100, k = i % 100;
        xs[r * 101 + k] = in[(size_t)(base + r) * HID + k];
    }
    __syncthreads();

    for (int t = tid; t < 400; t += 256) {
        int rq = t / 25, hq = t % 25;
        int r0 = rq * 4, h0 = hq * 4;
        float acc[4][4] = {};
        #pragma unroll 5
        for (int k = 0; k < HID; ++k) {
            float a0 = xs[(r0 + 0) * 101 + k];
            float a1 = xs[(r0 + 1) * 101 + k];
            float a2 = xs[(r0 + 2) * 101 + k];
            float a3 = xs[(r0 + 3) * 101 + k];
            float b0 = ws[k * 101 + h0 + 0];
            float b1 = ws[k * 101 + h0 + 1];
            float b2 = ws[k * 101 + h0 + 2];
            float b3 = ws[k * 101 + h0 + 3];
            acc[0][0] += a0 * b0; acc[0][1] += a0 * b1; acc[0][2] += a0 * b2; acc[0][3] += a0 * b3;
            acc[1][0] += a1 * b0; acc[1][1] += a1 * b1; acc[1][2] += a1 * b2; acc[1][3] += a1 * b3;
            acc[2][0] += a2 * b0; acc[2][1] += a2 * b1; acc[2][2] += a2 * b2; acc[2][3] += a2 * b3;
            acc[3][0] += a3 * b0; acc[3][1] += a3 * b1; acc[3][2] += a3 * b2; acc[3][3] += a3 * b3;
        }
        #pragma unroll
        for (int i = 0; i < 4; ++i)
            #pragma unroll
            for (int j = 0; j < 4; ++j)
                out[(size_t)(base + r0 + i) * HID + h0 + j] = __float2bfloat16(acc[i][j]);
    }
}

// ---------------------------------------------------------------------------
extern "C" void kernel_launch(void* const* d_in, const int* in_sizes, int n_in,
                              void* d_out, int out_size, void* d_ws, size_t ws_size,
                              hipStream_t stream)
{
    const int*   hyper = (const int*)  d_in[0];
    const int*   arows = (const int*)  d_in[1];
    const int*   acols = (const int*)  d_in[2];
    const float* avals = (const float*)d_in[3];
    const float* emb   = (const float*)d_in[4];
    const float* W1    = (const float*)d_in[5];
    const float* b1    = (const float*)d_in[6];
    const float* W2    = (const float*)d_in[7];
    const float* b2    = (const float*)d_in[8];

    float* out = (float*)d_out;
    char*  ws  = (char*)d_ws;

    int*             csr_c   = (int*)  (ws + OFF_CSR_C);
    float*           csr_v   = (float*)(ws + OFF_CSR_V);
    int*             row_st  = (int*)  (ws + OFF_ROWST);
    int*             cursor  = (int*)  (ws + OFF_CURSOR);
    __hip_bfloat16*  sup     = (__hip_bfloat16*)(ws + OFF_SUP);
    const unsigned*  sup_u   = (const unsigned*)(ws + OFF_SUP);

    const int nrows = BB * NN;

    // --- CSR build (A shared by both layers) ---
    hipMemsetAsync(cursor, 0, (size_t)BB * NN * sizeof(int), stream);
    k_hist   <<<4096, 256, 0, stream>>>(arows, cursor);
    k_scan   <<<BB,   512, 0, stream>>>(cursor, row_st);
    k_scatter<<<4096, 256, 0, stream>>>(arows, acols, avals, cursor, csr_c, csr_v);

    // 1) support1 = emb[hyper] @ W1              -> sup (bf16, ws)
    k_embed_gemm1<<<nrows / 64, 256, 0, stream>>>(hyper, emb, W1, sup);
    // 2) h1 = A @ support1 + b1                  -> d_out (fp32)
    k_spmm_lds<<<BB, 512, 0, stream>>>(row_st, csr_c, csr_v, sup_u, b1, out);
    // 3) support2 = h1 @ W2                      -> sup (bf16, ws)
    k_gemm2<<<nrows / 64, 256, 0, stream>>>(out, W2, sup);
    // 4) out = A @ support2 + b2                 -> d_out (fp32)
    k_spmm_lds<<<BB, 512, 0, stream>>>(row_st, csr_c, csr_v, sup_u, b2, out);
}

// Round 4
// 492.645 us; speedup vs baseline: 10.6366x; 1.9630x over previous
//
#include <hip/hip_runtime.h>

// Problem constants (match reference setup_inputs)
#define BB   512
#define NN   512
#define NNZ  8192
#define EMB  64
#define HID  100

// ---------------------------------------------------------------------------
// ws layout (bytes):
//   [0)          csr_c   int  [B*NNZ]          16,777,216
//   [16777216)   csr_v   f32  [B*NNZ]          16,777,216
//   [33554432)   row_st  int  [B*513]           1,050,624
//   [34605056)   cursor  int  [B*512]           1,048,576   (also histogram)
//   [35653632)   sup     bf16 [B*N*100]        52,428,800   (u32-pair packed)
//   [88082432)   w1t     bf16 [112][64]            14,336   (B^T padded)
//   [88096768)   w2t     bf16 [112][128]           28,672   (B^T k-padded)
// total 88,125,440  (ws >= 104.8 MB proven in round 1)
// ---------------------------------------------------------------------------
#define OFF_CSR_C   0
#define OFF_CSR_V   16777216
#define OFF_ROWST   33554432
#define OFF_CURSOR  34605056
#define OFF_SUP     35653632
#define OFF_W1T     88082432
#define OFF_W2T     88096768

typedef __attribute__((ext_vector_type(8))) short short8;
typedef __attribute__((ext_vector_type(4))) float floatx4;

// fp32 -> bf16 bits, round-to-nearest-even
__device__ __forceinline__ unsigned short f2bf(float f) {
    unsigned u = __float_as_uint(f);
    unsigned r = (u + 0x7fffu + ((u >> 16) & 1u)) >> 16;
    return (unsigned short)r;
}

__device__ __forceinline__ short8 pack8(float4 a, float4 b) {
    short8 s;
    s[0] = (short)f2bf(a.x); s[1] = (short)f2bf(a.y);
    s[2] = (short)f2bf(a.z); s[3] = (short)f2bf(a.w);
    s[4] = (short)f2bf(b.x); s[5] = (short)f2bf(b.y);
    s[6] = (short)f2bf(b.z); s[7] = (short)f2bf(b.w);
    return s;
}

// ---------------------------------------------------------------------------
// Prep: build transposed bf16 weight panels.
// w1t[h][k] : 112 x 64  (h >= 100 zero)
// w2t[h][k] : 112 x 128 (h >= 100 or k >= 100 zero)
// ---------------------------------------------------------------------------
__global__ __launch_bounds__(256) void k_prep(
    const float* __restrict__ W1, const float* __restrict__ W2,
    unsigned short* __restrict__ w1t, unsigned short* __restrict__ w2t)
{
    int id = blockIdx.x * 256 + threadIdx.x;
    if (id < 112 * 64) {
        int h = id >> 6, k = id & 63;
        float f = (h < 100) ? W1[k * 100 + h] : 0.f;
        w1t[id] = f2bf(f);
    }
    if (id < 112 * 128) {
        int h = id >> 7, k = id & 127;
        float f = (h < 100 && k < 100) ? W2[k * 100 + h] : 0.f;
        w2t[id] = f2bf(f);
    }
}

// ---------------------------------------------------------------------------
// CSR build: histogram -> per-batch scan -> scatter (A shared by both layers)
// ---------------------------------------------------------------------------
__global__ __launch_bounds__(256) void k_hist(
    const int* __restrict__ rows, int* __restrict__ counts)
{
    for (int idx = blockIdx.x * 256 + threadIdx.x; idx < BB * NNZ;
         idx += gridDim.x * 256) {
        int b = idx / NNZ;
        int r = rows[idx];
        atomicAdd(&counts[b * NN + r], 1);
    }
}

__global__ __launch_bounds__(512) void k_scan(
    int* __restrict__ cursor, int* __restrict__ row_start)
{
    __shared__ int s[NN];
    const int b = blockIdx.x, t = threadIdx.x;
    const int own = cursor[b * NN + t];
    s[t] = own;
    __syncthreads();
    for (int off = 1; off < NN; off <<= 1) {
        int v = (t >= off) ? s[t - off] : 0;
        __syncthreads();
        s[t] += v;
        __syncthreads();
    }
    row_start[b * 513 + t + 1] = s[t];
    if (t == 0) row_start[b * 513] = 0;
    cursor[b * NN + t] = s[t] - own;
}

__global__ __launch_bounds__(256) void k_scatter(
    const int* __restrict__ rows, const int* __restrict__ cols,
    const float* __restrict__ vals, int* __restrict__ cursor,
    int* __restrict__ csr_c, float* __restrict__ csr_v)
{
    for (int idx = blockIdx.x * 256 + threadIdx.x; idx < BB * NNZ;
         idx += gridDim.x * 256) {
        int b = idx / NNZ;
        int r = rows[idx];
        int pos = atomicAdd(&cursor[b * NN + r], 1);
        csr_c[(size_t)b * NNZ + pos] = cols[idx];
        csr_v[(size_t)b * NNZ + pos] = vals[idx];
    }
}

// ---------------------------------------------------------------------------
// GEMM1 (MFMA): sup = bf16( emb[hyper] @ W1 ).  No LDS.
// Per wave: 16 rows x 112 cols (7 col-tiles), K=64 (2 k-tiles).
// A frag loaded straight from emb (8 contiguous k per lane), B frags in regs.
// 1024 blocks x 4 waves x 4 rowblocks = 16384 rowblocks.
// ---------------------------------------------------------------------------
__global__ __launch_bounds__(256) void k_gemm1_mfma(
    const int* __restrict__ hyper, const float* __restrict__ emb,
    const unsigned short* __restrict__ w1t, unsigned short* __restrict__ sup)
{
    const int lane = threadIdx.x & 63, wave = threadIdx.x >> 6;
    const int l15 = lane & 15, g4 = lane >> 4;

    short8 bq[7][2];
    #pragma unroll
    for (int ct = 0; ct < 7; ++ct)
        #pragma unroll
        for (int kt = 0; kt < 2; ++kt)
            bq[ct][kt] = *(const short8*)(w1t + (ct * 16 + l15) * 64 + kt * 32 + g4 * 8);

    const int wsid = blockIdx.x * 4 + wave;          // 0..4095
    #pragma unroll 2
    for (int i = 0; i < 4; ++i) {
        const int  rb   = wsid * 4 + i;              // 0..16383
        const long base = (long)rb * 16;
        const int  rid  = hyper[base + l15];
        const float* ep = emb + (long)rid * EMB + g4 * 8;
        float4 f0 = *(const float4*)(ep);
        float4 f1 = *(const float4*)(ep + 4);
        float4 f2 = *(const float4*)(ep + 32);
        float4 f3 = *(const float4*)(ep + 36);
        short8 a0 = pack8(f0, f1);
        short8 a1 = pack8(f2, f3);

        floatx4 acc[7];
        #pragma unroll
        for (int ct = 0; ct < 7; ++ct) { acc[ct] = (floatx4)0.f; }
        #pragma unroll
        for (int ct = 0; ct < 7; ++ct) {
            acc[ct] = __builtin_amdgcn_mfma_f32_16x16x32_bf16(a0, bq[ct][0], acc[ct], 0, 0, 0);
            acc[ct] = __builtin_amdgcn_mfma_f32_16x16x32_bf16(a1, bq[ct][1], acc[ct], 0, 0, 0);
        }
        #pragma unroll
        for (int ct = 0; ct < 7; ++ct) {
            int col = ct * 16 + l15;
            if (col < HID) {
                #pragma unroll
                for (int r = 0; r < 4; ++r) {
                    long row = base + g4 * 4 + r;    // C: col=lane&15, row=(lane>>4)*4+reg
                    sup[row * HID + col] = f2bf(acc[ct][r]);
                }
            }
        }
    }
}

// ---------------------------------------------------------------------------
// GEMM2 (MFMA): sup = bf16( h1 @ W2 ), h1 fp32 (d_out). K=100 (4 k-tiles,
// zero-padded to 128). 7 col-tiles split across wave pairs (4 + 3) to cap
// VGPRs. 1024 blocks x 2 wavepairs x 8 rowblocks = 16384.
// ---------------------------------------------------------------------------
__global__ __launch_bounds__(256) void k_gemm2_mfma(
    const float* __restrict__ h1, const unsigned short* __restrict__ w2t,
    unsigned short* __restrict__ sup)
{
    const int lane = threadIdx.x & 63, wave = threadIdx.x >> 6;
    const int l15 = lane & 15, g4 = lane >> 4;
    const int ct0 = (wave & 1) ? 4 : 0;              // col-tile group: 0..3 / 4..6

    short8 bq[4][4];
    #pragma unroll
    for (int ctl = 0; ctl < 4; ++ctl) {
        int ct = ct0 + ctl;
        if (ct < 7)
            #pragma unroll
            for (int kt = 0; kt < 4; ++kt)
                bq[ctl][kt] = *(const short8*)(w2t + (ct * 16 + l15) * 128 + kt * 32 + g4 * 8);
    }

    const int wp = blockIdx.x * 2 + (wave >> 1);     // 0..2047
    #pragma unroll 2
    for (int i = 0; i < 8; ++i) {
        const int  rb   = wp * 8 + i;
        const long base = (long)rb * 16;
        const float* rp = h1 + (base + l15) * HID;

        short8 a[4];
        #pragma unroll
        for (int kt = 0; kt < 4; ++kt) {
            int koff = kt * 32 + g4 * 8;
            float4 f0 = make_float4(0.f, 0.f, 0.f, 0.f);
            float4 f1 = make_float4(0.f, 0.f, 0.f, 0.f);
            if (koff < HID)     f0 = *(const float4*)(rp + koff);
            if (koff + 4 < HID) f1 = *(const float4*)(rp + koff + 4);
            a[kt] = pack8(f0, f1);
        }

        floatx4 acc[4];
        #pragma unroll
        for (int ctl = 0; ctl < 4; ++ctl) { acc[ctl] = (floatx4)0.f; }
        #pragma unroll
        for (int ctl = 0; ctl < 4; ++ctl) {
            if (ct0 + ctl < 7) {
                #pragma unroll
                for (int kt = 0; kt < 4; ++kt)
                    acc[ctl] = __builtin_amdgcn_mfma_f32_16x16x32_bf16(a[kt], bq[ctl][kt], acc[ctl], 0, 0, 0);
            }
        }
        #pragma unroll
        for (int ctl = 0; ctl < 4; ++ctl) {
            if (ct0 + ctl < 7) {
                int col = (ct0 + ctl) * 16 + l15;
                if (col < HID) {
                    #pragma unroll
                    for (int r = 0; r < 4; ++r) {
                        long row = base + g4 * 4 + r;
                        sup[row * HID + col] = f2bf(acc[ctl][r]);
                    }
                }
            }
        }
    }
}

// ---------------------------------------------------------------------------
// SpMM + bias: lane-per-row, register accumulators.
// Block = (batch, h-half). LDS: sup half [512][26] u32 (bf16 pairs) = 52 KB
// -> 3 blocks/CU. Lane owns one row: loop its nnz (c,v prefetched one ahead),
// inner unrolled 25 LDS reads + 50 FMAs into float2 acc[25]. No shfl/atomics.
// ---------------------------------------------------------------------------
__global__ __launch_bounds__(512) void k_spmm(
    const int* __restrict__ row_st, const int* __restrict__ csr_c,
    const float* __restrict__ csr_v, const unsigned* __restrict__ sup,
    const float* __restrict__ bias, float* __restrict__ out)
{
    __shared__ unsigned xh[NN * 26];

    const int tid  = threadIdx.x;
    const int b    = blockIdx.x >> 1;
    const int half = blockIdx.x & 1;

    // stage: sup[b] columns [half*25, half*25+25) -> xh[r][0..25)
    const unsigned* sb = sup + (size_t)b * NN * 50 + half * 25;
    for (int idx = tid; idx < NN * 25; idx += 512) {
        int r = idx / 25, t = idx - r * 25;
        xh[r * 26 + t] = sb[(size_t)r * 50 + t];
    }
    __syncthreads();

    const int lane = tid & 63, wave = tid >> 6;
    const int r = wave * 64 + lane;                  // this lane's row

    const int s = row_st[b * 513 + r];
    const int e = row_st[b * 513 + r + 1];

    const int*   cc = csr_c + (size_t)b * NNZ;
    const float* vv = csr_v + (size_t)b * NNZ;

    float2 acc[25];
    #pragma unroll
    for (int t = 0; t < 25; ++t) acc[t] = make_float2(0.f, 0.f);

    int c = 0; float v = 0.f;
    if (s < e) { c = cc[s]; v = vv[s]; }
    for (int j = s; j < e; ++j) {
        int cn = 0; float vn = 0.f;
        if (j + 1 < e) { cn = cc[j + 1]; vn = vv[j + 1]; }
        const unsigned* xp = &xh[c * 26];
        #pragma unroll
        for (int t = 0; t < 25; ++t) {
            unsigned x = xp[t];
            acc[t].x += v * __uint_as_float(x << 16);
            acc[t].y += v * __uint_as_float(x & 0xffff0000u);
        }
        c = cn; v = vn;
    }

    float*       op = out + ((size_t)b * NN + r) * HID + half * 50;
    const float* bp = bias + half * 50;
    #pragma unroll
    for (int t = 0; t < 25; ++t) {
        float2 o;
        o.x = acc[t].x + bp[2 * t];
        o.y = acc[t].y + bp[2 * t + 1];
        *(float2*)(op + 2 * t) = o;
    }
}

// ---------------------------------------------------------------------------
extern "C" void kernel_launch(void* const* d_in, const int* in_sizes, int n_in,
                              void* d_out, int out_size, void* d_ws, size_t ws_size,
                              hipStream_t stream)
{
    const int*   hyper = (const int*)  d_in[0];
    const int*   arows = (const int*)  d_in[1];
    const int*   acols = (const int*)  d_in[2];
    const float* avals = (const float*)d_in[3];
    const float* emb   = (const float*)d_in[4];
    const float* W1    = (const float*)d_in[5];
    const float* b1    = (const float*)d_in[6];
    const float* W2    = (const float*)d_in[7];
    const float* b2    = (const float*)d_in[8];

    float* out = (float*)d_out;
    char*  ws  = (char*)d_ws;

    int*            csr_c  = (int*)  (ws + OFF_CSR_C);
    float*          csr_v  = (float*)(ws + OFF_CSR_V);
    int*            row_st = (int*)  (ws + OFF_ROWST);
    int*            cursor = (int*)  (ws + OFF_CURSOR);
    unsigned short* sup16  = (unsigned short*)(ws + OFF_SUP);
    const unsigned* sup_u  = (const unsigned*)(ws + OFF_SUP);
    unsigned short* w1t    = (unsigned short*)(ws + OFF_W1T);
    unsigned short* w2t    = (unsigned short*)(ws + OFF_W2T);

    // prep transposed bf16 weights
    k_prep<<<56, 256, 0, stream>>>(W1, W2, w1t, w2t);

    // CSR build (A shared by both layers)
    hipMemsetAsync(cursor, 0, (size_t)BB * NN * sizeof(int), stream);
    k_hist   <<<4096, 256, 0, stream>>>(arows, cursor);
    k_scan   <<<BB,   512, 0, stream>>>(cursor, row_st);
    k_scatter<<<4096, 256, 0, stream>>>(arows, acols, avals, cursor, csr_c, csr_v);

    // 1) sup = bf16(emb[hyper] @ W1)
    k_gemm1_mfma<<<1024, 256, 0, stream>>>(hyper, emb, w1t, sup16);
    // 2) h1 = A @ sup + b1 -> d_out (fp32)
    k_spmm<<<BB * 2, 512, 0, stream>>>(row_st, csr_c, csr_v, sup_u, b1, out);
    // 3) sup = bf16(h1 @ W2)
    k_gemm2_mfma<<<1024, 256, 0, stream>>>(out, w2t, sup16);
    // 4) out = A @ sup + b2 -> d_out (fp32)
    k_spmm<<<BB * 2, 512, 0, stream>>>(row_st, csr_c, csr_v, sup_u, b2, out);
}

// Round 5
// 340.273 us; speedup vs baseline: 15.3996x; 1.4478x over previous
//
#include <hip/hip_runtime.h>

// Problem constants (match reference setup_inputs)
#define BB   512
#define NN   512
#define NNZ  8192
#define EMB  64
#define HID  100

// ---------------------------------------------------------------------------
// ws layout (bytes):
//   [0)          csr_c   int  [B*NNZ]          16,777,216
//   [16777216)   csr_v   f32  [B*NNZ]          16,777,216
//   [33554432)   row_st  int  [B*513]           1,050,624
//   [34605056)   (free)
//   [35653632)   sup     bf16 [B*N*100]        52,428,800   (u32-pair packed)
//   [88082432)   w1t     bf16 [112][64]            14,336   (B^T padded)
//   [88096768)   w2t     bf16 [112][128]           28,672   (B^T k-padded)
// ---------------------------------------------------------------------------
#define OFF_CSR_C   0
#define OFF_CSR_V   16777216
#define OFF_ROWST   33554432
#define OFF_SUP     35653632
#define OFF_W1T     88082432
#define OFF_W2T     88096768

typedef __attribute__((ext_vector_type(8))) short short8;
typedef __attribute__((ext_vector_type(4))) float floatx4;

// fp32 -> bf16 bits, round-to-nearest-even
__device__ __forceinline__ unsigned short f2bf(float f) {
    unsigned u = __float_as_uint(f);
    unsigned r = (u + 0x7fffu + ((u >> 16) & 1u)) >> 16;
    return (unsigned short)r;
}

__device__ __forceinline__ short8 pack8(float4 a, float4 b) {
    short8 s;
    s[0] = (short)f2bf(a.x); s[1] = (short)f2bf(a.y);
    s[2] = (short)f2bf(a.z); s[3] = (short)f2bf(a.w);
    s[4] = (short)f2bf(b.x); s[5] = (short)f2bf(b.y);
    s[6] = (short)f2bf(b.z); s[7] = (short)f2bf(b.w);
    return s;
}

// ---------------------------------------------------------------------------
// Prep: build transposed bf16 weight panels.
// ---------------------------------------------------------------------------
__global__ __launch_bounds__(256) void k_prep(
    const float* __restrict__ W1, const float* __restrict__ W2,
    unsigned short* __restrict__ w1t, unsigned short* __restrict__ w2t)
{
    int id = blockIdx.x * 256 + threadIdx.x;
    if (id < 112 * 64) {
        int h = id >> 6, k = id & 63;
        float f = (h < 100) ? W1[k * 100 + h] : 0.f;
        w1t[id] = f2bf(f);
    }
    if (id < 112 * 128) {
        int h = id >> 7, k = id & 127;
        float f = (h < 100 && k < 100) ? W2[k * 100 + h] : 0.f;
        w2t[id] = f2bf(f);
    }
}

// ---------------------------------------------------------------------------
// CSR build, batch-local: one block per batch. rows staged in LDS, histogram
// via ds_add on 512 LDS counters, Hillis-Steele LDS scan, scatter with LDS
// cursors into the block's PRIVATE 64KB CSR window (single-XCD L2, written
// back once). Replaces memset+hist+scan+scatter (was ~210us, 340MB writes).
// ---------------------------------------------------------------------------
__global__ __launch_bounds__(512) void k_csr_build(
    const int* __restrict__ rows, const int* __restrict__ cols,
    const float* __restrict__ vals, int* __restrict__ row_start,
    int* __restrict__ csr_c, float* __restrict__ csr_v)
{
    __shared__ int rl[NNZ];       // 32 KB: this batch's row indices
    __shared__ int cnt[NN];       // counts -> scatter cursor
    __shared__ int sc[NN];        // scan workspace

    const int b   = blockIdx.x;
    const int tid = threadIdx.x;  // 0..511 == NN

    const int* rb = rows + (size_t)b * NNZ;

    cnt[tid] = 0;
    __syncthreads();

    #pragma unroll
    for (int i = 0; i < NNZ / 512; ++i) {
        int idx = tid + i * 512;
        int r = rb[idx];
        rl[idx] = r;
        atomicAdd(&cnt[r], 1);
    }
    __syncthreads();

    // exclusive scan (Hillis-Steele over 512)
    const int own = cnt[tid];
    sc[tid] = own;
    __syncthreads();
    #pragma unroll
    for (int off = 1; off < NN; off <<= 1) {
        int v = (tid >= off) ? sc[tid - off] : 0;
        __syncthreads();
        sc[tid] += v;
        __syncthreads();
    }
    row_start[b * 513 + tid + 1] = sc[tid];
    if (tid == 0) row_start[b * 513] = 0;
    cnt[tid] = sc[tid] - own;     // exclusive scan -> cursor
    __syncthreads();

    const int*   cb = cols + (size_t)b * NNZ;
    const float* vb = vals + (size_t)b * NNZ;
    int*         oc = csr_c + (size_t)b * NNZ;
    float*       ov = csr_v + (size_t)b * NNZ;

    #pragma unroll
    for (int i = 0; i < NNZ / 512; ++i) {
        int idx = tid + i * 512;
        int   c = cb[idx];          // coalesced reads
        float v = vb[idx];
        int pos = atomicAdd(&cnt[rl[idx]], 1);
        oc[pos] = c;                // scattered, but within private 32KB window
        ov[pos] = v;
    }
}

// ---------------------------------------------------------------------------
// GEMM1 (MFMA): sup = bf16( emb[hyper] @ W1 ).  No LDS.
// ---------------------------------------------------------------------------
__global__ __launch_bounds__(256) void k_gemm1_mfma(
    const int* __restrict__ hyper, const float* __restrict__ emb,
    const unsigned short* __restrict__ w1t, unsigned short* __restrict__ sup)
{
    const int lane = threadIdx.x & 63, wave = threadIdx.x >> 6;
    const int l15 = lane & 15, g4 = lane >> 4;

    short8 bq[7][2];
    #pragma unroll
    for (int ct = 0; ct < 7; ++ct)
        #pragma unroll
        for (int kt = 0; kt < 2; ++kt)
            bq[ct][kt] = *(const short8*)(w1t + (ct * 16 + l15) * 64 + kt * 32 + g4 * 8);

    const int wsid = blockIdx.x * 4 + wave;
    #pragma unroll 2
    for (int i = 0; i < 4; ++i) {
        const int  rb   = wsid * 4 + i;
        const long base = (long)rb * 16;
        const int  rid  = hyper[base + l15];
        const float* ep = emb + (long)rid * EMB + g4 * 8;
        float4 f0 = *(const float4*)(ep);
        float4 f1 = *(const float4*)(ep + 4);
        float4 f2 = *(const float4*)(ep + 32);
        float4 f3 = *(const float4*)(ep + 36);
        short8 a0 = pack8(f0, f1);
        short8 a1 = pack8(f2, f3);

        floatx4 acc[7];
        #pragma unroll
        for (int ct = 0; ct < 7; ++ct) { acc[ct] = (floatx4)0.f; }
        #pragma unroll
        for (int ct = 0; ct < 7; ++ct) {
            acc[ct] = __builtin_amdgcn_mfma_f32_16x16x32_bf16(a0, bq[ct][0], acc[ct], 0, 0, 0);
            acc[ct] = __builtin_amdgcn_mfma_f32_16x16x32_bf16(a1, bq[ct][1], acc[ct], 0, 0, 0);
        }
        #pragma unroll
        for (int ct = 0; ct < 7; ++ct) {
            int col = ct * 16 + l15;
            if (col < HID) {
                #pragma unroll
                for (int r = 0; r < 4; ++r) {
                    long row = base + g4 * 4 + r;
                    sup[row * HID + col] = f2bf(acc[ct][r]);
                }
            }
        }
    }
}

// ---------------------------------------------------------------------------
// GEMM2 (MFMA): sup = bf16( h1 @ W2 ), h1 fp32 (d_out).
// ---------------------------------------------------------------------------
__global__ __launch_bounds__(256) void k_gemm2_mfma(
    const float* __restrict__ h1, const unsigned short* __restrict__ w2t,
    unsigned short* __restrict__ sup)
{
    const int lane = threadIdx.x & 63, wave = threadIdx.x >> 6;
    const int l15 = lane & 15, g4 = lane >> 4;
    const int ct0 = (wave & 1) ? 4 : 0;

    short8 bq[4][4];
    #pragma unroll
    for (int ctl = 0; ctl < 4; ++ctl) {
        int ct = ct0 + ctl;
        if (ct < 7)
            #pragma unroll
            for (int kt = 0; kt < 4; ++kt)
                bq[ctl][kt] = *(const short8*)(w2t + (ct * 16 + l15) * 128 + kt * 32 + g4 * 8);
    }

    const int wp = blockIdx.x * 2 + (wave >> 1);
    #pragma unroll 2
    for (int i = 0; i < 8; ++i) {
        const int  rb   = wp * 8 + i;
        const long base = (long)rb * 16;
        const float* rp = h1 + (base + l15) * HID;

        short8 a[4];
        #pragma unroll
        for (int kt = 0; kt < 4; ++kt) {
            int koff = kt * 32 + g4 * 8;
            float4 f0 = make_float4(0.f, 0.f, 0.f, 0.f);
            float4 f1 = make_float4(0.f, 0.f, 0.f, 0.f);
            if (koff < HID)     f0 = *(const float4*)(rp + koff);
            if (koff + 4 < HID) f1 = *(const float4*)(rp + koff + 4);
            a[kt] = pack8(f0, f1);
        }

        floatx4 acc[4];
        #pragma unroll
        for (int ctl = 0; ctl < 4; ++ctl) { acc[ctl] = (floatx4)0.f; }
        #pragma unroll
        for (int ctl = 0; ctl < 4; ++ctl) {
            if (ct0 + ctl < 7) {
                #pragma unroll
                for (int kt = 0; kt < 4; ++kt)
                    acc[ctl] = __builtin_amdgcn_mfma_f32_16x16x32_bf16(a[kt], bq[ctl][kt], acc[ctl], 0, 0, 0);
            }
        }
        #pragma unroll
        for (int ctl = 0; ctl < 4; ++ctl) {
            if (ct0 + ctl < 7) {
                int col = (ct0 + ctl) * 16 + l15;
                if (col < HID) {
                    #pragma unroll
                    for (int r = 0; r < 4; ++r) {
                        long row = base + g4 * 4 + r;
                        sup[row * HID + col] = f2bf(acc[ctl][r]);
                    }
                }
            }
        }
    }
}

// ---------------------------------------------------------------------------
// SpMM + bias: lane-per-row, register accumulators.
// ---------------------------------------------------------------------------
__global__ __launch_bounds__(512) void k_spmm(
    const int* __restrict__ row_st, const int* __restrict__ csr_c,
    const float* __restrict__ csr_v, const unsigned* __restrict__ sup,
    const float* __restrict__ bias, float* __restrict__ out)
{
    __shared__ unsigned xh[NN * 26];

    const int tid  = threadIdx.x;
    const int b    = blockIdx.x >> 1;
    const int half = blockIdx.x & 1;

    const unsigned* sb = sup + (size_t)b * NN * 50 + half * 25;
    for (int idx = tid; idx < NN * 25; idx += 512) {
        int r = idx / 25, t = idx - r * 25;
        xh[r * 26 + t] = sb[(size_t)r * 50 + t];
    }
    __syncthreads();

    const int lane = tid & 63, wave = tid >> 6;
    const int r = wave * 64 + lane;

    const int s = row_st[b * 513 + r];
    const int e = row_st[b * 513 + r + 1];

    const int*   cc = csr_c + (size_t)b * NNZ;
    const float* vv = csr_v + (size_t)b * NNZ;

    float2 acc[25];
    #pragma unroll
    for (int t = 0; t < 25; ++t) acc[t] = make_float2(0.f, 0.f);

    int c = 0; float v = 0.f;
    if (s < e) { c = cc[s]; v = vv[s]; }
    for (int j = s; j < e; ++j) {
        int cn = 0; float vn = 0.f;
        if (j + 1 < e) { cn = cc[j + 1]; vn = vv[j + 1]; }
        const unsigned* xp = &xh[c * 26];
        #pragma unroll
        for (int t = 0; t < 25; ++t) {
            unsigned x = xp[t];
            acc[t].x += v * __uint_as_float(x << 16);
            acc[t].y += v * __uint_as_float(x & 0xffff0000u);
        }
        c = cn; v = vn;
    }

    float*       op = out + ((size_t)b * NN + r) * HID + half * 50;
    const float* bp = bias + half * 50;
    #pragma unroll
    for (int t = 0; t < 25; ++t) {
        float2 o;
        o.x = acc[t].x + bp[2 * t];
        o.y = acc[t].y + bp[2 * t + 1];
        *(float2*)(op + 2 * t) = o;
    }
}

// ---------------------------------------------------------------------------
extern "C" void kernel_launch(void* const* d_in, const int* in_sizes, int n_in,
                              void* d_out, int out_size, void* d_ws, size_t ws_size,
                              hipStream_t stream)
{
    const int*   hyper = (const int*)  d_in[0];
    const int*   arows = (const int*)  d_in[1];
    const int*   acols = (const int*)  d_in[2];
    const float* avals = (const float*)d_in[3];
    const float* emb   = (const float*)d_in[4];
    const float* W1    = (const float*)d_in[5];
    const float* b1    = (const float*)d_in[6];
    const float* W2    = (const float*)d_in[7];
    const float* b2    = (const float*)d_in[8];

    float* out = (float*)d_out;
    char*  ws  = (char*)d_ws;

    int*            csr_c  = (int*)  (ws + OFF_CSR_C);
    float*          csr_v  = (float*)(ws + OFF_CSR_V);
    int*            row_st = (int*)  (ws + OFF_ROWST);
    unsigned short* sup16  = (unsigned short*)(ws + OFF_SUP);
    const unsigned* sup_u  = (const unsigned*)(ws + OFF_SUP);
    unsigned short* w1t    = (unsigned short*)(ws + OFF_W1T);
    unsigned short* w2t    = (unsigned short*)(ws + OFF_W2T);

    // prep transposed bf16 weights
    k_prep<<<56, 256, 0, stream>>>(W1, W2, w1t, w2t);

    // CSR build, batch-local (A shared by both layers)
    k_csr_build<<<BB, 512, 0, stream>>>(arows, acols, avals, row_st, csr_c, csr_v);

    // 1) sup = bf16(emb[hyper] @ W1)
    k_gemm1_mfma<<<1024, 256, 0, stream>>>(hyper, emb, w1t, sup16);
    // 2) h1 = A @ sup + b1 -> d_out (fp32)
    k_spmm<<<BB * 2, 512, 0, stream>>>(row_st, csr_c, csr_v, sup_u, b1, out);
    // 3) sup = bf16(h1 @ W2)
    k_gemm2_mfma<<<1024, 256, 0, stream>>>(out, w2t, sup16);
    // 4) out = A @ sup + b2 -> d_out (fp32)
    k_spmm<<<BB * 2, 512, 0, stream>>>(row_st, csr_c, csr_v, sup_u, b2, out);
}